// Round 4
// baseline (150.602 us; speedup 1.0000x reference)
//
#include <hip/hip_runtime.h>
#include <math.h>

#define EPS_F 1e-6f
#define NCHUNK 128   // 32 tokens per chunk

// ---- workspace layout (float offsets), ~22 MB ----
#define OFF_WCQ 0                            // folded q weights [256][256]
#define OFF_WCK (OFF_WCQ + 65536)            // folded k weights [256][256]
#define OFF_BV  (OFF_WCK + 65536)            // folded v bias [256]
#define OFF_VC  (OFF_BV + 256)               // dwconv output [256][4096]
#define OFF_PS  (OFF_VC + 256*4096)          // partial Sm [8 h][128 chunk][64][64]
#define OFF_PSV (OFF_PS + 8*NCHUNK*4096)     // partial sv [8 h][128 chunk][64]
#define OFF_SM  (OFF_PSV + 8*NCHUNK*64)      // Sm [8][64*64]
#define OFF_SV  (OFF_SM + 8*4096)            // sv [8][64]

// Fold hedgehog linear into 1x1x1 conv: Wcq[h*64+e,c] = sum_d Wmq[e,d]*Wq[h*64+d,c]
__global__ __launch_bounds__(256) void k_combine(
    const float* __restrict__ Wq, const float* __restrict__ Wk,
    const float* __restrict__ Wmq, const float* __restrict__ Wmk,
    const float* __restrict__ Wmv, const float* __restrict__ bmv,
    const float* __restrict__ bv, float* __restrict__ ws)
{
    int row = blockIdx.x;        // h*64+e
    int c = threadIdx.x;
    int h = row >> 6, e = row & 63;
    float aq = 0.f, ak = 0.f;
    for (int d = 0; d < 64; ++d) {
        float mq = Wmq[e*64 + d];
        float mk = Wmk[e*64 + d];
        int src = (h*64 + d)*256 + c;
        aq = fmaf(mq, Wq[src], aq);
        ak = fmaf(mk, Wk[src], ak);
    }
    ws[OFF_WCQ + row*256 + c] = aq;
    ws[OFF_WCK + row*256 + c] = ak;
    if (c == 0) {
        float av = 0.f;
        for (int d = 0; d < 64; ++d) av = fmaf(Wmv[e*64 + d], bv[h*64 + d], av);
        ws[OFF_BV + row] = av + bmv[e];
    }
}

// depthwise 3x3x3, zero pad, bias folded downstream. Block = one z-plane of one
// channel; stage 3 z-planes in LDS -> 3 global loads + 27 LDS reads per output.
__global__ __launch_bounds__(256) void k_dwconv(
    const float* __restrict__ x, const float* __restrict__ Wv, float* __restrict__ vc)
{
    __shared__ float pl[3][256];
    int t = threadIdx.x;
    int z = blockIdx.x;          // 0..15
    int c = blockIdx.y;          // 0..255
    const float* xc = x + (size_t)c*4096;
    #pragma unroll
    for (int kz = 0; kz < 3; ++kz) {
        int zz = z + kz - 1;
        pl[kz][t] = (zz >= 0 && zz < 16) ? xc[zz*256 + t] : 0.f;
    }
    __syncthreads();
    int y = t >> 4, xx = t & 15;
    const float* wc = Wv + c*27;     // uniform -> scalar loads
    float acc = 0.f;
    #pragma unroll
    for (int kz = 0; kz < 3; ++kz) {
        #pragma unroll
        for (int ky = 0; ky < 3; ++ky) {
            int yy = y + ky - 1;
            bool vy = (yy >= 0) && (yy < 16);
            int yc = yy < 0 ? 0 : (yy > 15 ? 15 : yy);
            #pragma unroll
            for (int kx = 0; kx < 3; ++kx) {
                int xv = xx + kx - 1;
                bool v = vy && (xv >= 0) && (xv < 16);
                int xc2 = xv < 0 ? 0 : (xv > 15 ? 15 : xv);
                float val = pl[kz][yc*16 + xc2];
                acc = fmaf(wc[(kz*3 + ky)*3 + kx], v ? val : 0.f, acc);
            }
        }
    }
    vc[(size_t)c*4096 + z*256 + t] = acc;
}

// Per (hb 0..3, chunk of 32 tokens): K-proj GEMM (K=256) + V-proj (K=64,
// block-diag) -> exp± features in LDS -> partial Sm±/sv± outer products.
// Grid (128,4) = 512 blocks, ~35 KB LDS -> 2+ blocks/CU.
__global__ __launch_bounds__(256) void k_kv_fused(
    const float* __restrict__ X, const float* __restrict__ bmk,
    const float* __restrict__ Wmv, float* __restrict__ ws)
{
    __shared__ float smem[8704];
    float* Xs  = smem;           // [64][32]   phase 1
    float* Wsh = smem + 2048;    // [64][68]   phase 1
    float* kfp = smem;           // [32][68]   phase 2/3
    float* kfm = smem + 2176;
    float* vfp = smem + 4352;
    float* vfm = smem + 6528;

    int t = threadIdx.x;
    int chunk = blockIdx.x;      // 0..127
    int hb = blockIdx.y;         // 0..3
    int n0 = chunk * 32;
    int e4 = (t & 15) * 4;       // 16 groups x 4 = 64 dims
    int n2 = (t >> 4) * 2;       // 16 groups x 2 = 32 tokens
    int lc = t >> 6, ln = t & 63;

    float accK[2][4], accV[2][4];
    #pragma unroll
    for (int i = 0; i < 2; ++i)
        #pragma unroll
        for (int j = 0; j < 4; ++j) { accK[i][j] = 0.f; accV[i][j] = 0.f; }

    // ---- K-projection GEMM, K=256 ----
    const float* Wck = ws + OFF_WCK;
    for (int c0 = 0; c0 < 256; c0 += 64) {
        #pragma unroll
        for (int i = 0; i < 8; ++i) {
            int idx = i*256 + t, cc = idx >> 5, nn = idx & 31;
            Xs[cc*32 + nn] = X[(size_t)(c0 + cc)*4096 + n0 + nn];
        }
        #pragma unroll
        for (int i = 0; i < 16; ++i)
            Wsh[ln*68 + lc*16 + i] = Wck[(size_t)(hb*64 + lc*16 + i)*256 + c0 + ln];
        __syncthreads();
        #pragma unroll 8
        for (int c = 0; c < 64; ++c) {
            float2 xv2 = *(const float2*)&Xs[c*32 + n2];
            float4 wv4 = *(const float4*)&Wsh[c*68 + e4];
            float xv[2] = {xv2.x, xv2.y};
            float wv[4] = {wv4.x, wv4.y, wv4.z, wv4.w};
            #pragma unroll
            for (int ii = 0; ii < 2; ++ii)
                #pragma unroll
                for (int jj = 0; jj < 4; ++jj)
                    accK[ii][jj] = fmaf(xv[ii], wv[jj], accK[ii][jj]);
        }
        __syncthreads();
    }

    // ---- V-projection GEMM, K=64 (block-diagonal head) ----
    {
        const float* vcb = ws + OFF_VC + (size_t)hb*64*4096;
        #pragma unroll
        for (int i = 0; i < 8; ++i) {
            int idx = i*256 + t, dd = idx >> 5, nn = idx & 31;
            Xs[dd*32 + nn] = vcb[(size_t)dd*4096 + n0 + nn];
        }
        #pragma unroll
        for (int i = 0; i < 16; ++i) {
            int idx = i*256 + t, dd = idx & 63, ee = idx >> 6;
            Wsh[dd*68 + ee] = Wmv[ee*64 + dd];   // coalesced global read
        }
        __syncthreads();
        #pragma unroll 8
        for (int d = 0; d < 64; ++d) {
            float2 xv2 = *(const float2*)&Xs[d*32 + n2];
            float4 wv4 = *(const float4*)&Wsh[d*68 + e4];
            float xv[2] = {xv2.x, xv2.y};
            float wv[4] = {wv4.x, wv4.y, wv4.z, wv4.w};
            #pragma unroll
            for (int ii = 0; ii < 2; ++ii)
                #pragma unroll
                for (int jj = 0; jj < 4; ++jj)
                    accV[ii][jj] = fmaf(xv[ii], wv[jj], accV[ii][jj]);
        }
        __syncthreads();
    }

    // ---- bias + exp± into LDS [n][a], rows padded to 68 ----
    float bk[4], bvv[4];
    #pragma unroll
    for (int j = 0; j < 4; ++j) { bk[j] = bmk[e4 + j]; bvv[j] = ws[OFF_BV + hb*64 + e4 + j]; }
    #pragma unroll
    for (int ii = 0; ii < 2; ++ii) {
        float pk[4], mk_[4], pv[4], mv[4];
        #pragma unroll
        for (int jj = 0; jj < 4; ++jj) {
            float a = accK[ii][jj] + bk[jj];
            pk[jj] = __expf(a);  mk_[jj] = __expf(-a);
            float b = accV[ii][jj] + bvv[jj];
            pv[jj] = __expf(b);  mv[jj] = __expf(-b);
        }
        int r = (n2 + ii)*68 + e4;
        *(float4*)&kfp[r] = make_float4(pk[0], pk[1], pk[2], pk[3]);
        *(float4*)&kfm[r] = make_float4(mk_[0], mk_[1], mk_[2], mk_[3]);
        *(float4*)&vfp[r] = make_float4(pv[0], pv[1], pv[2], pv[3]);
        *(float4*)&vfm[r] = make_float4(mv[0], mv[1], mv[2], mv[3]);
    }
    __syncthreads();

    // ---- outer products over 32 tokens ----
    int a4 = e4, f4 = (t >> 4) * 4;
    float aSp[4][4], aSm[4][4], svp[4], svm[4];
    #pragma unroll
    for (int i = 0; i < 4; ++i) {
        svp[i] = 0.f; svm[i] = 0.f;
        #pragma unroll
        for (int j = 0; j < 4; ++j) { aSp[i][j] = 0.f; aSm[i][j] = 0.f; }
    }
    #pragma unroll 4
    for (int n = 0; n < 32; ++n) {
        float4 kp4 = *(const float4*)&kfp[n*68 + a4];
        float4 km4 = *(const float4*)&kfm[n*68 + a4];
        float4 vp4 = *(const float4*)&vfp[n*68 + f4];
        float4 vm4 = *(const float4*)&vfm[n*68 + f4];
        float kp[4] = {kp4.x, kp4.y, kp4.z, kp4.w};
        float km[4] = {km4.x, km4.y, km4.z, km4.w};
        float vp[4] = {vp4.x, vp4.y, vp4.z, vp4.w};
        float vm[4] = {vm4.x, vm4.y, vm4.z, vm4.w};
        #pragma unroll
        for (int ai = 0; ai < 4; ++ai) {
            svp[ai] += kp[ai];  svm[ai] += km[ai];
            #pragma unroll
            for (int fi = 0; fi < 4; ++fi) {
                aSp[ai][fi] = fmaf(kp[ai], vp[fi], aSp[ai][fi]);
                aSm[ai][fi] = fmaf(km[ai], vm[fi], aSm[ai][fi]);
            }
        }
    }
    float* pSp = ws + OFF_PS + (size_t)(hb*NCHUNK + chunk)*4096;
    float* pSm = ws + OFF_PS + (size_t)((hb + 4)*NCHUNK + chunk)*4096;
    #pragma unroll
    for (int ai = 0; ai < 4; ++ai) {
        *(float4*)&pSp[(a4 + ai)*64 + f4] = make_float4(aSp[ai][0], aSp[ai][1], aSp[ai][2], aSp[ai][3]);
        *(float4*)&pSm[(a4 + ai)*64 + f4] = make_float4(aSm[ai][0], aSm[ai][1], aSm[ai][2], aSm[ai][3]);
    }
    if (t < 16) {
        float* pvp = ws + OFF_PSV + (size_t)(hb*NCHUNK + chunk)*64;
        float* pvm = ws + OFF_PSV + (size_t)((hb + 4)*NCHUNK + chunk)*64;
        *(float4*)&pvp[a4] = make_float4(svp[0], svp[1], svp[2], svp[3]);
        *(float4*)&pvm[a4] = make_float4(svm[0], svm[1], svm[2], svm[3]);
    }
}

__global__ __launch_bounds__(256) void k_reduce(float* __restrict__ ws)
{
    int idx = blockIdx.x*256 + threadIdx.x;
    if (idx < 8*4096) {
        int h = idx >> 12, r = idx & 4095;
        float s = 0.f;
        #pragma unroll 8
        for (int c = 0; c < NCHUNK; ++c) s += ws[OFF_PS + (size_t)(h*NCHUNK + c)*4096 + r];
        ws[OFF_SM + idx] = s;
    } else if (idx < 8*4096 + 512) {
        int j = idx - 8*4096;
        int h = j >> 6, e = j & 63;
        float s = 0.f;
        #pragma unroll 8
        for (int c = 0; c < NCHUNK; ++c) s += ws[OFF_PSV + (size_t)(h*NCHUNK + c)*64 + e];
        ws[OFF_SV + j] = s;
    }
}

// Per (hb, chunk of 32 tokens): Q-proj GEMM -> qf± [n][a] in LDS ->
// out[h] = (qf·Sm[h]) / (qf·sv[h] + eps) for h=hb (plus), hb+4 (minus).
// Thread tile: 32 e-groups x 8 n-groups (e2=(t&31)*2, n4=(t>>5)*4).
__global__ __launch_bounds__(256) void k_q_out(
    const float* __restrict__ X, const float* __restrict__ bmq,
    const float* __restrict__ ws, float* __restrict__ out)
{
    __shared__ float smem[8768];
    float* Xs  = smem;           // [64][32] phase 1
    float* Wsh = smem + 2048;    // [64][68] phase 1
    float* qfp = smem;           // [32][68] phase 2/3
    float* qfm = smem + 2176;
    float* Sms = smem + 4352;    // [64][68]
    float* svs = smem + 8704;    // [64]

    int t = threadIdx.x;
    int chunk = blockIdx.x;      // 0..127
    int hb = blockIdx.y;         // 0..3
    int n0 = chunk * 32;
    int e2 = (t & 31) * 2;       // 32 groups x 2 = 64 dims
    int n4 = (t >> 5) * 4;       // 8 groups x 4 = 32 tokens
    int lc = t >> 6, ln = t & 63;

    float accQ[4][2];            // [n][e]
    #pragma unroll
    for (int i = 0; i < 4; ++i) { accQ[i][0] = 0.f; accQ[i][1] = 0.f; }

    const float* Wcq = ws + OFF_WCQ;
    for (int c0 = 0; c0 < 256; c0 += 64) {
        #pragma unroll
        for (int i = 0; i < 8; ++i) {
            int idx = i*256 + t, cc = idx >> 5, nn = idx & 31;
            Xs[cc*32 + nn] = X[(size_t)(c0 + cc)*4096 + n0 + nn];
        }
        #pragma unroll
        for (int i = 0; i < 16; ++i)
            Wsh[ln*68 + lc*16 + i] = Wcq[(size_t)(hb*64 + lc*16 + i)*256 + c0 + ln];
        __syncthreads();
        #pragma unroll 8
        for (int c = 0; c < 64; ++c) {
            float4 xv4 = *(const float4*)&Xs[c*32 + n4];
            float2 wv2 = *(const float2*)&Wsh[c*68 + e2];
            float xv[4] = {xv4.x, xv4.y, xv4.z, xv4.w};
            float wv[2] = {wv2.x, wv2.y};
            #pragma unroll
            for (int ii = 0; ii < 4; ++ii)
                #pragma unroll
                for (int jj = 0; jj < 2; ++jj)
                    accQ[ii][jj] = fmaf(xv[ii], wv[jj], accQ[ii][jj]);
        }
        __syncthreads();
    }

    // exp± into LDS [n][a]
    float bq[2] = {bmq[e2], bmq[e2 + 1]};
    #pragma unroll
    for (int ii = 0; ii < 4; ++ii) {
        float a0 = accQ[ii][0] + bq[0];
        float a1 = accQ[ii][1] + bq[1];
        int r = (n4 + ii)*68 + e2;
        *(float2*)&qfp[r] = make_float2(__expf(a0),  __expf(a1));
        *(float2*)&qfm[r] = make_float2(__expf(-a0), __expf(-a1));
    }

    for (int s = 0; s < 2; ++s) {
        int h = hb + 4*s;
        __syncthreads();
        const float* Smg = ws + OFF_SM + (size_t)h*4096;
        #pragma unroll
        for (int i = 0; i < 16; ++i) {
            int idx = i*256 + t;
            Sms[(idx >> 6)*68 + (idx & 63)] = Smg[idx];
        }
        if (t < 64) svs[t] = ws[OFF_SV + h*64 + t];
        __syncthreads();

        const float* qf = s ? qfm : qfp;
        float accO[2][4];        // [e][n]
        float den[4] = {0.f, 0.f, 0.f, 0.f};
        #pragma unroll
        for (int j = 0; j < 2; ++j)
            #pragma unroll
            for (int i = 0; i < 4; ++i) accO[j][i] = 0.f;
        #pragma unroll 4
        for (int a = 0; a < 64; ++a) {
            float sva = svs[a];
            float2 sm2 = *(const float2*)&Sms[a*68 + e2];
            float sm[2] = {sm2.x, sm2.y};
            float qv[4];
            #pragma unroll
            for (int i = 0; i < 4; ++i) qv[i] = qf[(n4 + i)*68 + a];  // half-wave broadcast
            #pragma unroll
            for (int i = 0; i < 4; ++i) {
                den[i] = fmaf(qv[i], sva, den[i]);
                #pragma unroll
                for (int j = 0; j < 2; ++j)
                    accO[j][i] = fmaf(sm[j], qv[i], accO[j][i]);
            }
        }
        float r[4];
        #pragma unroll
        for (int i = 0; i < 4; ++i) r[i] = 1.f / (den[i] + EPS_F);
        #pragma unroll
        for (int j = 0; j < 2; ++j)
            *(float4*)&out[(size_t)(h*64 + e2 + j)*4096 + n0 + n4] =
                make_float4(accO[j][0]*r[0], accO[j][1]*r[1], accO[j][2]*r[2], accO[j][3]*r[3]);
    }
}

extern "C" void kernel_launch(void* const* d_in, const int* in_sizes, int n_in,
                              void* d_out, int out_size, void* d_ws, size_t ws_size,
                              hipStream_t stream) {
    const float* x   = (const float*)d_in[0];
    const float* Wq  = (const float*)d_in[1];
    const float* Wk  = (const float*)d_in[2];
    const float* Wv  = (const float*)d_in[3];
    const float* bv  = (const float*)d_in[4];
    const float* Wmq = (const float*)d_in[5];
    const float* bmq = (const float*)d_in[6];
    const float* Wmk = (const float*)d_in[7];
    const float* bmk = (const float*)d_in[8];
    const float* Wmv = (const float*)d_in[9];
    const float* bmv = (const float*)d_in[10];
    float* out = (float*)d_out;
    float* ws  = (float*)d_ws;

    k_combine<<<256, 256, 0, stream>>>(Wq, Wk, Wmq, Wmk, Wmv, bmv, bv, ws);
    k_dwconv<<<dim3(16, 256), 256, 0, stream>>>(x, Wv, ws + OFF_VC);
    k_kv_fused<<<dim3(NCHUNK, 4), 256, 0, stream>>>(x, bmk, Wmv, ws);
    k_reduce<<<130, 256, 0, stream>>>(ws);
    k_q_out<<<dim3(NCHUNK, 4), 256, 0, stream>>>(x, bmq, ws, out);
}